// Round 2
// baseline (780.759 us; speedup 1.0000x reference)
//
#include <hip/hip_runtime.h>

#define NSTR 8
#define DM 2048
#define NK 120
#define NKP 128

// ============================================================================
// PATH: mean8 (streaming) -> proj (split-K GEMM, no atomics) -> cayley
// ws layout: xa [npos][2048] f32 at offset 0; zp [npos][8][128] f32 after.
// zp is interleaved by position so cayley reads one contiguous 4 KB block/pos.
// ============================================================================

// ---------------- kernel A: xa = mean over 8 streams (pure streaming) --------
// One block per position; thread t owns float4 columns t and t+256 -> every
// load instruction is 64 contiguous lanes x 16 B = 1 KB; 16 loads in flight.
__global__ __launch_bounds__(256)
void mean8(const float4* __restrict__ s4, float4* __restrict__ xa4, int pbase) {
    const int t = threadIdx.x;
    const size_t p = blockIdx.x;                       // local position
    const float4* src = s4 + (size_t)(pbase + p) * (NSTR * DM / 4);
    float4 a = src[t];
    float4 b = src[t + 256];
#pragma unroll
    for (int n = 1; n < 8; ++n) {
        const float4 u = src[(size_t)n * (DM / 4) + t];
        const float4 w = src[(size_t)n * (DM / 4) + t + 256];
        a.x += u.x; a.y += u.y; a.z += u.z; a.w += u.w;
        b.x += w.x; b.y += w.y; b.z += w.z; b.w += w.w;
    }
    a.x *= 0.125f; a.y *= 0.125f; a.z *= 0.125f; a.w *= 0.125f;
    b.x *= 0.125f; b.y *= 0.125f; b.z *= 0.125f; b.w *= 0.125f;
    xa4[p * (DM / 4) + t] = a;
    xa4[p * (DM / 4) + t + 256] = b;
}

// ---------------- kernel B: z-partials = xa * W^T (tiled fp32 GEMM) ----------
// grid = (npos/128) * 8 k-slices; block 256; 2 wg/CU (64 KB LDS).
// Register-staged pipeline (T14): next sub-tile's 16 global loads issue BEFORE
// compute so L3/HBM latency hides under the 4K-FMA compute phase.
// Slice s writes zp[pos][s][k] -> zero atomics, no zero-init.
__global__ __launch_bounds__(256, 2)
void proj(const float* __restrict__ xa, const float* __restrict__ Wm,
          float* __restrict__ zp, int npos) {
    __shared__ float4 sxa[128 * 16];  // 32 KB: xa tile [128 p][64 d], XOR-swizzled
    __shared__ float4 sw[128 * 16];   // 32 KB: W  tile [128 k][64 d], rows>=120 = 0

    const int t = threadIdx.x;
    const int slice = blockIdx.x & 7;   // 0..7  K-slice (256 d each)
    const int ptile = blockIdx.x >> 3;  // position tile
    const int pos0 = ptile * 128;
    const int typ = t >> 4;   // p-octet
    const int txk = t & 15;   // k-octet
    const int c = t & 15;     // staged chunk column
    const int rbase = t >> 4; // staged row base

    float4 ra[8], rw[8];
    float acc[8][8];
#pragma unroll
    for (int i = 0; i < 8; ++i)
#pragma unroll
        for (int j = 0; j < 8; ++j) acc[i][j] = 0.f;

    // ---- prologue: load sub 0 into registers ----
    {
        const int ds0 = slice * 256;
#pragma unroll
        for (int r = 0; r < 8; ++r) {
            const int p = rbase + 16 * r;
            ra[r] = *(const float4*)(xa + (size_t)(pos0 + p) * DM + ds0 + c * 4);
        }
#pragma unroll
        for (int r = 0; r < 8; ++r) {
            const int k = rbase + 16 * r;
            rw[r] = (k < NK) ? *(const float4*)(Wm + (size_t)k * DM + ds0 + c * 4)
                             : make_float4(0.f, 0.f, 0.f, 0.f);
        }
    }

#pragma unroll 1
    for (int sub = 0; sub < 4; ++sub) {
        // ---- write staged registers to (swizzled) LDS ----
#pragma unroll
        for (int r = 0; r < 8; ++r) {
            const int p = rbase + 16 * r;
            sxa[p * 16 + (c ^ (p >> 3))] = ra[r];
        }
#pragma unroll
        for (int r = 0; r < 8; ++r) {
            const int k = rbase + 16 * r;
            sw[k * 16 + (c ^ (k >> 3))] = rw[r];
        }
        __syncthreads();

        // ---- prefetch NEXT sub-tile into registers (overlaps compute) ----
        if (sub < 3) {
            const int ds0 = slice * 256 + (sub + 1) * 64;
#pragma unroll
            for (int r = 0; r < 8; ++r) {
                const int p = rbase + 16 * r;
                ra[r] = *(const float4*)(xa + (size_t)(pos0 + p) * DM + ds0 + c * 4);
            }
#pragma unroll
            for (int r = 0; r < 8; ++r) {
                const int k = rbase + 16 * r;
                rw[r] = (k < NK) ? *(const float4*)(Wm + (size_t)k * DM + ds0 + c * 4)
                                 : make_float4(0.f, 0.f, 0.f, 0.f);
            }
        }

        // ---- GEMM micro-tile: per d-quad, 16 b128 LDS reads feed 256 fmac ----
        for (int dq = 0; dq < 16; ++dq) {
            float4 a[8];
#pragma unroll
            for (int i = 0; i < 8; ++i) a[i] = sxa[(typ * 8 + i) * 16 + (dq ^ typ)];
#pragma unroll
            for (int j = 0; j < 8; ++j) {
                const float4 bv = sw[(txk * 8 + j) * 16 + (dq ^ txk)];
#pragma unroll
                for (int i = 0; i < 8; ++i) {
                    acc[i][j] = fmaf(a[i].x, bv.x, acc[i][j]);
                    acc[i][j] = fmaf(a[i].y, bv.y, acc[i][j]);
                    acc[i][j] = fmaf(a[i].z, bv.z, acc[i][j]);
                    acc[i][j] = fmaf(a[i].w, bv.w, acc[i][j]);
                }
            }
        }
        __syncthreads();
    }

    // ---- store this slice's partial into [pos][slice][128] (no atomics) ----
#pragma unroll
    for (int i = 0; i < 8; ++i) {
        float* dst = zp + ((size_t)(pos0 + typ * 8 + i) * 8 + slice) * NKP + txk * 8;
        *(float4*)dst = make_float4(acc[i][0], acc[i][1], acc[i][2], acc[i][3]);
        *((float4*)dst + 1) = make_float4(acc[i][4], acc[i][5], acc[i][6], acc[i][7]);
    }
}

// ---------------- kernel C: Cayley transform + block-Frobenius ---------------
// One wave per position; 16x16 Gauss-Jordan in registers via shfl.
// zp layout [pos][NPARTS][NKP]: the wave loads its position's NPARTS*512 B as
// coalesced float4s, reduces slices in registers (+bvec), parks the 128-float
// z-row in LDS. No scattered global gathers.
template <int NPARTS>
__global__ __launch_bounds__(256)
void cayley_k(const float* __restrict__ zp, const float* __restrict__ bvec,
              float* __restrict__ out, int pbase) {
    __shared__ float zrow[4][NKP];
    const int t = threadIdx.x;
    const int wave = t >> 6;
    const int l = t & 63;
    const int pos = blockIdx.x * 4 + wave;   // local position
    const int j = l & 15;
    const int g = l >> 4;

    // ---- cooperative coalesced z load + slice reduction ----
    {
        const float4* src = (const float4*)(zp + (size_t)pos * NPARTS * NKP);
        float4 s = make_float4(0.f, 0.f, 0.f, 0.f);
#pragma unroll
        for (int q = 0; q < (NPARTS + 1) / 2; ++q) {
            const int idx = l + 64 * q;              // col4 = idx&31 == l&31
            if (idx < NPARTS * 32) {
                const float4 v = src[idx];
                s.x += v.x; s.y += v.y; s.z += v.z; s.w += v.w;
            }
        }
        // partner lane (l^32) holds the other half of this col4's slices
        s.x += __shfl_xor(s.x, 32, 64);
        s.y += __shfl_xor(s.y, 32, 64);
        s.z += __shfl_xor(s.z, 32, 64);
        s.w += __shfl_xor(s.w, 32, 64);
        if (l < 32) {
            if (l < 30) {  // bvec has 120 floats; col4 29 covers 116..119
                const float4 b4 = ((const float4*)bvec)[l];
                s.x += b4.x; s.y += b4.y; s.z += b4.z; s.w += b4.w;
            }
            ((float4*)&zrow[wave][0])[l] = s;
        }
    }
    __syncthreads();

    float m[4], x[4];
#pragma unroll
    for (int r = 0; r < 4; ++r) {
        const int i = 4 * r + g;
        float a;
        if (i < j) {
            a = zrow[wave][(i * (31 - i)) / 2 + (j - i - 1)];
        } else if (i > j) {
            a = -zrow[wave][(j * (31 - j)) / 2 + (i - j - 1)];
        } else {
            a = 0.f;
        }
        const float d = (i == j) ? 1.f : 0.f;
        m[r] = d + a;   // M = I + A
        x[r] = d - a;   // X = I - A  (becomes Q after solve)
    }

#pragma unroll
    for (int k = 0; k < 16; ++k) {
        const int rr = k >> 2;
        const int src_row = (k & 3) << 4;
        const float mk  = __shfl(m[rr], src_row | j, 64);
        const float xk  = __shfl(x[rr], src_row | j, 64);
        const float mkk = __shfl(m[rr], src_row | k, 64);
        const float rk = 1.0f / mkk;
#pragma unroll
        for (int r = 0; r < 4; ++r) {
            const float mik = __shfl(m[r], (g << 4) | k, 64);
            const float f = (4 * r + g == k) ? 0.f : mik * rk;
            m[r] = fmaf(-f, mk, m[r]);
            x[r] = fmaf(-f, xk, x[r]);
        }
    }

    float h[4];
#pragma unroll
    for (int r = 0; r < 4; ++r) {
        const int i = 4 * r + g;
        const float mdiag = __shfl(m[r], (g << 4) | i, 64);
        const float q = x[r] / mdiag;
        float s = q * q;
        s += __shfl_xor(s, 1, 64);
        s += __shfl_xor(s, 16, 64);
        h[r] = s * 0.5f;
    }
    if (((j & 1) == 0) && ((g & 1) == 0)) {
        const int col = j >> 1;
#pragma unroll
        for (int r = 0; r < 4; ++r) {
            const int row = 2 * r + (g >> 1);
            out[(size_t)(pbase + pos) * 64 + row * 8 + col] = h[r];
        }
    }
}

// ============================================================================
// FALLBACK PATH (workspace too small): fused mean+proj with atomics into a
// single z buffer [pos][1][128], then cayley_k<1>.
// ============================================================================
#define TM 128
#define DSLICE 256
#define SD 64

__global__ void zero_ws(float4* z4) {
    z4[(size_t)blockIdx.x * 256 + threadIdx.x] = make_float4(0.f, 0.f, 0.f, 0.f);
}

__global__ __launch_bounds__(256, 2)
void mean_proj_fused(const float* __restrict__ streams, const float* __restrict__ W,
                     float* __restrict__ z) {
    __shared__ float4 sxa[TM * 16];
    __shared__ float4 sw[NKP * 16];

    const int t = threadIdx.x;
    const int bid = blockIdx.x;
    const int slice = bid >> 6;
    const int ptile = bid & 63;
    const int pos0 = ptile * TM;
    const int typ = t >> 4;
    const int txk = t & 15;

    float acc[8][8];
#pragma unroll
    for (int i = 0; i < 8; ++i)
#pragma unroll
        for (int j = 0; j < 8; ++j) acc[i][j] = 0.f;

    for (int sub = 0; sub < 4; ++sub) {
        const int ds0 = slice * DSLICE + sub * SD;
#pragma unroll
        for (int r = 0; r < 8; ++r) {
            const int item = t + 256 * r;
            const int p = item >> 4;
            const int dq = item & 15;
            const float4* src = (const float4*)(streams
                + (size_t)(pos0 + p) * NSTR * DM + ds0 + dq * 4);
            float4 v = src[0];
#pragma unroll
            for (int n = 1; n < 8; ++n) {
                const float4 u = src[n * (DM / 4)];
                v.x += u.x; v.y += u.y; v.z += u.z; v.w += u.w;
            }
            v.x *= 0.125f; v.y *= 0.125f; v.z *= 0.125f; v.w *= 0.125f;
            sxa[p * 16 + (dq ^ (p >> 3))] = v;
        }
#pragma unroll
        for (int r = 0; r < 8; ++r) {
            const int item = t + 256 * r;
            const int k = item >> 4;
            const int dq = item & 15;
            float4 v = make_float4(0.f, 0.f, 0.f, 0.f);
            if (k < NK) v = *(const float4*)(W + (size_t)k * DM + ds0 + dq * 4);
            sw[k * 16 + (dq ^ (k >> 3))] = v;
        }
        __syncthreads();

        for (int dq = 0; dq < 16; ++dq) {
            float4 a[8];
#pragma unroll
            for (int i = 0; i < 8; ++i) a[i] = sxa[(typ * 8 + i) * 16 + (dq ^ typ)];
#pragma unroll
            for (int j = 0; j < 8; ++j) {
                const float4 bv = sw[(txk * 8 + j) * 16 + (dq ^ txk)];
#pragma unroll
                for (int i = 0; i < 8; ++i) {
                    acc[i][j] = fmaf(a[i].x, bv.x, acc[i][j]);
                    acc[i][j] = fmaf(a[i].y, bv.y, acc[i][j]);
                    acc[i][j] = fmaf(a[i].z, bv.z, acc[i][j]);
                    acc[i][j] = fmaf(a[i].w, bv.w, acc[i][j]);
                }
            }
        }
        __syncthreads();
    }

#pragma unroll
    for (int i = 0; i < 8; ++i) {
        const size_t p = (size_t)pos0 + typ * 8 + i;
#pragma unroll
        for (int j = 0; j < 8; ++j) {
            const int k = txk * 8 + j;
            if (k < NK) atomicAdd(&z[p * NKP + k], acc[i][j]);
        }
    }
}

// ---------------- launcher ---------------------------------------------------
extern "C" void kernel_launch(void* const* d_in, const int* in_sizes, int n_in,
                              void* d_out, int out_size, void* d_ws, size_t ws_size,
                              hipStream_t stream) {
    const float* streams = (const float*)d_in[0];  // [2,4096,8,2048] fp32
    const float* W       = (const float*)d_in[1];  // [120,2048] fp32
    const float* bvec    = (const float*)d_in[2];  // [120] fp32
    float* out = (float*)d_out;                    // [2,4096,8,8] fp32

    const size_t TOTPOS = 8192;
    const size_t XA_FULL = TOTPOS * DM * sizeof(float);          // 64 MiB
    const size_t ZP_FULL = 8 * TOTPOS * NKP * sizeof(float);     // 32 MiB

    int nb = 0;
    size_t npos = 0;
    if (ws_size >= XA_FULL + ZP_FULL)               { nb = 1; npos = 8192; }
    else if (ws_size >= (XA_FULL + ZP_FULL) / 2)    { nb = 2; npos = 4096; }

    if (nb > 0) {
        float* xa = (float*)d_ws;
        float* zp = (float*)((char*)d_ws + npos * DM * sizeof(float));
        for (int b = 0; b < nb; ++b) {
            const int pbase = (int)(b * npos);
            mean8<<<(int)npos, 256, 0, stream>>>(
                (const float4*)streams, (float4*)xa, pbase);
            proj<<<(int)((npos / 128) * 8), 256, 0, stream>>>(xa, W, zp, (int)npos);
            cayley_k<8><<<(int)(npos / 4), 256, 0, stream>>>(zp, bvec, out, pbase);
        }
    } else {
        // fallback: fused path (needs only 4 MiB ws)
        float* z = (float*)d_ws;
        zero_ws<<<1024, 256, 0, stream>>>((float4*)d_ws);
        mean_proj_fused<<<512, 256, 0, stream>>>(streams, W, z);
        cayley_k<1><<<2048, 256, 0, stream>>>(z, bvec, out, 0);
    }
}